// Round 4
// baseline (4076.505 us; speedup 1.0000x reference)
//
#include <hip/hip_runtime.h>
#include <math.h>

#define NB    4096   // batch N
#define FEAT  1024
#define MSUP  512    // SUPPORT
#define G4    4096   // 4*FEAT
#define NWAYS 20     // n_ways fixed to 20 per setup_inputs()

typedef _Float16 f16;
typedef f16 f16x8 __attribute__((ext_vector_type(8)));
typedef f16 f16x4 __attribute__((ext_vector_type(4)));
typedef float f32x16 __attribute__((ext_vector_type(16)));
typedef unsigned int u32;
#define GLOBAL_AS __attribute__((address_space(1)))
#define LDS_AS    __attribute__((address_space(3)))

__device__ __forceinline__ void load_lds16(const void* g, void* l) {
    __builtin_amdgcn_global_load_lds((const GLOBAL_AS u32*)g, (LDS_AS u32*)l, 16, 0, 0);
}

// ---------------- f16 MFMA NT GEMM, 32x32x16 frags ----------------
// C[m,n] = sum_k A[m,k]*B[n,k]; optional f16 initC (same ldc) + two f32 col biases.
// LDS layout = fragment-read order: 16B chunk q of a tile holds global
// (row = (q>>7)*32 + (q&31), kchunk = ((q>>6)&1)*2 + ((q>>5)&1)), so the MFMA
// frag read af[i][h] is ds_read_b128 at ((i*2+h)*64 + lane)*16 — lane-sequential,
// zero bank conflicts by construction. (R3 lesson: 64B rows can't be de-conflicted
// by in-row swizzles; permute the whole tile instead.)
template<int BM, int BN, int WROWS, int WCOLS, bool OUTF16, bool HASINIT, bool HASBIAS>
__global__ __launch_bounds__(256) void mfma_nt(
    void* __restrict__ Cv, int ldc,
    const f16* __restrict__ A, int lda,
    const f16* __restrict__ B, int ldb, int K,
    const f16* __restrict__ initC,
    const float* __restrict__ bias1, const float* __restrict__ bias2)
{
    constexpr int BK = 32;
    constexpr int WM = BM / WROWS, WN = BN / WCOLS;
    constexpr int FM = WM / 32,   FN = WN / 32;
    __shared__ f16 As[BM * BK];
    __shared__ f16 Bs[BN * BK];
    const int tid  = threadIdx.x;
    const int lane = tid & 63;
    const int wrow = (tid >> 6) % WROWS, wcol = (tid >> 6) / WROWS;
    const int bm = blockIdx.y * BM, bn = blockIdx.x * BN;
    const int lc = lane & 31;   // row/col within 32-frag
    const int lh = lane >> 5;   // k-subgroup

    f32x16 acc[FM][FN] = {};

    #pragma unroll 1
    for (int k0 = 0; k0 < K; k0 += BK) {
        __syncthreads();
        #pragma unroll
        for (int t = 0; t < (BM * 4) / 256; ++t) {
            int q = t * 256 + tid;
            int row = (q >> 7) * 32 + (q & 31);
            int kc  = ((q >> 6) & 1) * 2 + ((q >> 5) & 1);
            load_lds16(A + (size_t)(bm + row) * lda + k0 + kc * 8,
                       &As[((size_t)t * 256 + (tid & ~63)) * 8]);
        }
        #pragma unroll
        for (int t = 0; t < (BN * 4) / 256; ++t) {
            int q = t * 256 + tid;
            int row = (q >> 7) * 32 + (q & 31);
            int kc  = ((q >> 6) & 1) * 2 + ((q >> 5) & 1);
            load_lds16(B + (size_t)(bn + row) * ldb + k0 + kc * 8,
                       &Bs[((size_t)t * 256 + (tid & ~63)) * 8]);
        }
        __syncthreads();
        // frag reads: lane-sequential b128, conflict-free
        f16x8 af[FM][2], bf[FN][2];
        #pragma unroll
        for (int i = 0; i < FM; ++i) {
            int ib = (wrow * WM) / 32 + i;
            #pragma unroll
            for (int h = 0; h < 2; ++h)
                af[i][h] = *(const f16x8*)&As[(((ib * 2 + h) * 64) + lane) * 8];
        }
        #pragma unroll
        for (int j = 0; j < FN; ++j) {
            int jb = (wcol * WN) / 32 + j;
            #pragma unroll
            for (int h = 0; h < 2; ++h)
                bf[j][h] = *(const f16x8*)&Bs[(((jb * 2 + h) * 64) + lane) * 8];
        }
        #pragma unroll
        for (int h = 0; h < 2; ++h)
            #pragma unroll
            for (int i = 0; i < FM; ++i)
                #pragma unroll
                for (int j = 0; j < FN; ++j)
                    acc[i][j] = __builtin_amdgcn_mfma_f32_32x32x16_f16(af[i][h], bf[j][h], acc[i][j], 0, 0, 0);
    }

    // epilogue: C/D layout col=lane&31, row=(reg&3)+8*(reg>>2)+4*(lane>>5)
    #pragma unroll
    for (int i = 0; i < FM; ++i) {
        #pragma unroll
        for (int j = 0; j < FN; ++j) {
            const int col   = bn + wcol * WN + j * 32 + lc;
            const int rbase = bm + wrow * WM + i * 32 + 4 * lh;
            float badd = 0.f;
            if (HASBIAS) badd = bias1[col] + bias2[col];
            #pragma unroll
            for (int reg = 0; reg < 16; ++reg) {
                int row = rbase + (reg & 3) + 8 * (reg >> 2);
                size_t off = (size_t)row * ldc + col;
                float v = acc[i][j][reg] + badd;
                if (HASINIT) v += (float)initC[off];
                if (OUTF16) ((f16*)Cv)[off] = (f16)v;
                else        ((float*)Cv)[off] = v;
            }
        }
    }
}

// -------- softmax along contiguous rows; in f32 [rows][4096] -> out f16 --------
__global__ __launch_bounds__(256) void softmax_rows_kernel(
    const float* __restrict__ X, f16* __restrict__ Y)
{
    const int row = blockIdx.x;
    const float* x = X + (size_t)row * NB;
    f16* y = Y + (size_t)row * NB;
    const int tid = threadIdx.x;
    float v[16];
    float mx = -1e30f;
    #pragma unroll
    for (int i = 0; i < 16; ++i) { v[i] = x[tid + (i << 8)]; mx = fmaxf(mx, v[i]); }
    #pragma unroll
    for (int off = 32; off > 0; off >>= 1) mx = fmaxf(mx, __shfl_down(mx, off));
    __shared__ float sm[4];
    if ((tid & 63) == 0) sm[tid >> 6] = mx;
    __syncthreads();
    mx = fmaxf(fmaxf(sm[0], sm[1]), fmaxf(sm[2], sm[3]));
    float s = 0.f;
    #pragma unroll
    for (int i = 0; i < 16; ++i) { v[i] = __expf(v[i] - mx); s += v[i]; }
    #pragma unroll
    for (int off = 32; off > 0; off >>= 1) s += __shfl_down(s, off);
    __shared__ float ss[4];
    if ((tid & 63) == 0) ss[tid >> 6] = s;
    __syncthreads();
    s = ss[0] + ss[1] + ss[2] + ss[3];
    const float inv = 1.f / s;
    #pragma unroll
    for (int i = 0; i < 16; ++i) y[tid + (i << 8)] = (f16)(v[i] * inv);
}

// -------- transpose: in [R][C] (Tin) -> out f16 [C][R] --------
template<typename Tin>
__global__ __launch_bounds__(256) void transpose_f16_kernel(
    const Tin* __restrict__ in, f16* __restrict__ out, int R, int C)
{
    __shared__ f16 t[64][65];
    const int r0 = blockIdx.y * 64, c0 = blockIdx.x * 64;
    const int lr = threadIdx.x & 63, lw = threadIdx.x >> 6;
    #pragma unroll
    for (int i = 0; i < 16; ++i) {
        int rr = lw * 16 + i;
        t[rr][lr] = (f16)in[(size_t)(r0 + rr) * C + c0 + lr];
    }
    __syncthreads();
    #pragma unroll
    for (int i = 0; i < 16; ++i) {
        int cc = lw * 16 + i;
        out[(size_t)(c0 + cc) * R + r0 + lr] = t[lr][cc];
    }
}

// -------- conversions --------
__global__ __launch_bounds__(256) void cvt_f16_kernel(
    const float* __restrict__ in, f16* __restrict__ out, int n)
{
    int idx = (blockIdx.x * 256 + threadIdx.x) * 4;
    if (idx < n) {
        float4 v = *(const float4*)(in + idx);
        f16x4 o = {(f16)v.x, (f16)v.y, (f16)v.z, (f16)v.w};
        *(f16x4*)(out + idx) = o;
    }
}

// f [NB][1024] f32 -> xh[:,1024:2048] f16 (row stride 2048)
__global__ __launch_bounds__(256) void cvt_f_to_xh(
    const float* __restrict__ f, f16* __restrict__ xh)
{
    int idx = (blockIdx.x * 256 + threadIdx.x) * 4;
    int n = idx >> 10, k = idx & 1023;
    float4 v = *(const float4*)(f + idx);
    f16x4 o = {(f16)v.x, (f16)v.y, (f16)v.z, (f16)v.w};
    *(f16x4*)(xh + (size_t)n * 2048 + 1024 + k) = o;
}

// W_f[j][k] = Wih[j][k], k<1024  (f16)
__global__ __launch_bounds__(256) void cvt_wf(
    const float* __restrict__ Wih, f16* __restrict__ Wf)
{
    int idx = (blockIdx.x * 256 + threadIdx.x) * 4;
    int j = idx >> 10, k = idx & 1023;
    float4 v = *(const float4*)(Wih + (size_t)j * 2048 + k);
    f16x4 o = {(f16)v.x, (f16)v.y, (f16)v.z, (f16)v.w};
    *(f16x4*)(Wf + idx) = o;
}

// W_cat[j][0:1024] = Wih[j][1024:2048]; W_cat[j][1024:2048] = Whh[j][:]
__global__ __launch_bounds__(256) void cvt_wcat(
    const float* __restrict__ Wih, const float* __restrict__ Whh, f16* __restrict__ Wc)
{
    int idx = (blockIdx.x * 256 + threadIdx.x) * 4;
    int j = idx >> 11, k = idx & 2047;
    const float* src = (k < 1024) ? (Wih + (size_t)j * 2048 + 1024 + k)
                                  : (Whh + (size_t)j * 1024 + (k - 1024));
    float4 v = *(const float4*)src;
    f16x4 o = {(f16)v.x, (f16)v.y, (f16)v.z, (f16)v.w};
    *(f16x4*)(Wc + idx) = o;
}

// -------- LSTM cell; gates f16 [NB][4F] (i,f,g,o); h = o*tanh(c)+f --------
// Writes f32 h to d_out and f16 h into xh[:,1024:2048].
__global__ __launch_bounds__(256) void lstm_cell_kernel(
    const f16* __restrict__ gates, const float* __restrict__ f,
    float* __restrict__ c, float* __restrict__ h, f16* __restrict__ xh, int first)
{
    const int idx = blockIdx.x * 256 + threadIdx.x;
    const int n = idx >> 10, k = idx & 1023;
    const f16* g = gates + (size_t)n * G4;
    float ig = (float)g[k], fg = (float)g[k + 1024];
    float gg = (float)g[k + 2048], og = (float)g[k + 3072];
    float i_ = 1.f / (1.f + __expf(-ig));
    float f_ = 1.f / (1.f + __expf(-fg));
    float g_ = tanhf(gg);
    float o_ = 1.f / (1.f + __expf(-og));
    float cn = i_ * g_ + (first ? 0.f : f_ * c[idx]);
    c[idx] = cn;
    float hn = o_ * tanhf(cn) + f[idx];
    h[idx] = hn;
    xh[(size_t)n * 2048 + 1024 + k] = (f16)hn;
}

extern "C" void kernel_launch(void* const* d_in, const int* in_sizes, int n_in,
                              void* d_out, int out_size, void* d_ws, size_t ws_size,
                              hipStream_t stream) {
    const float* f   = (const float*)d_in[0];   // [NB, FEAT]
    const float* G   = (const float*)d_in[1];   // [MSUP, FEAT]
    const float* Wih = (const float*)d_in[2];   // [G4, 2*FEAT]
    const float* Whh = (const float*)d_in[3];   // [G4, FEAT]
    const float* bih = (const float*)d_in[4];   // [G4]
    const float* bhh = (const float*)d_in[5];   // [G4]
    float* h = (float*)d_out;                   // [NB, FEAT]

    char* W = (char*)d_ws;
    f16*   xh      = (f16*)(W);                          // 16 MB [NB][2048]: cols 0:1024=r, 1024:2048=h (init f)
    f16*   pre_h   = (f16*)(W + (size_t)(16 << 20));     // 32 MB [NB][G4]
    f16*   gates_h = (f16*)(W + (size_t)(48 << 20));     // 32 MB [NB][G4]
    float* aT      = (float*)(W + (size_t)(80 << 20));   //  8 MB [MSUP][NB]
    f16*   aTh     = (f16*)(W + (size_t)(88 << 20));     //  4 MB [MSUP][NB]
    f16*   a_h     = (f16*)(W + (size_t)(92 << 20));     //  4 MB [NB][MSUP]
    float* c       = (float*)(W + (size_t)(96 << 20));   // 16 MB [NB][FEAT]
    f16*   W_f     = (f16*)(W + (size_t)(112 << 20));    //  8 MB [G4][FEAT]
    f16*   W_cat   = (f16*)(W + (size_t)(120 << 20));    // 16 MB [G4][2048]
    f16*   G_h     = (f16*)(W + (size_t)(136 << 20));    //  1 MB [MSUP][FEAT]
    f16*   GT_h    = (f16*)(W + (size_t)(137 << 20));    //  1 MB [FEAT][MSUP]

    const f16* NF = nullptr;
    const dim3 blk(256);

    // one-time conversions (every call — ws is re-poisoned)
    cvt_f_to_xh<<<(NB * FEAT) / 1024, blk, 0, stream>>>(f, xh);
    cvt_wf<<<(G4 * FEAT) / 1024, blk, 0, stream>>>(Wih, W_f);
    cvt_wcat<<<(G4 * 2 * FEAT) / 1024, blk, 0, stream>>>(Wih, Whh, W_cat);
    cvt_f16_kernel<<<(MSUP * FEAT) / 1024, blk, 0, stream>>>(G, G_h, MSUP * FEAT);
    transpose_f16_kernel<float><<<dim3(FEAT / 64, MSUP / 64), blk, 0, stream>>>(G, GT_h, MSUP, FEAT);

    // pre = f @ W_f^T + b_ih + b_hh   (constant across iterations)
    mfma_nt<128, 128, 2, 2, true, false, true><<<dim3(G4 / 128, NB / 128), blk, 0, stream>>>(
        pre_h, G4,
        xh + 1024, 2048, W_f, FEAT, FEAT,
        NF, bih, bhh);

    for (int it = 0; it < NWAYS; ++it) {
        // aT[m][n] = G[m]·h[n]  (h lives at xh[:,1024:2048])
        mfma_nt<64, 128, 2, 2, false, false, false><<<dim3(NB / 128, MSUP / 64), blk, 0, stream>>>(
            aT, NB,
            G_h, FEAT, xh + 1024, 2048, FEAT,
            NF, nullptr, nullptr);

        softmax_rows_kernel<<<MSUP, blk, 0, stream>>>(aT, aTh);

        // a_h[n][m] = aTh[m][n]
        transpose_f16_kernel<f16><<<dim3(NB / 64, MSUP / 64), blk, 0, stream>>>(aTh, a_h, MSUP, NB);

        // r[n][kf] = sum_m a[n][m]*GT[kf][m]  → written into xh[:,0:1024] (ldc=2048)
        mfma_nt<128, 128, 2, 2, true, false, false><<<dim3(FEAT / 128, NB / 128), blk, 0, stream>>>(
            xh, 2048,
            a_h, MSUP, GT_h, MSUP, MSUP,
            NF, nullptr, nullptr);

        // gates = pre + [r|h] @ W_cat^T   (single pass, K=2048)
        mfma_nt<128, 128, 2, 2, true, true, false><<<dim3(G4 / 128, NB / 128), blk, 0, stream>>>(
            gates_h, G4,
            xh, 2048, W_cat, 2048, 2048,
            pre_h, nullptr, nullptr);

        lstm_cell_kernel<<<(NB * FEAT) / 256, blk, 0, stream>>>(gates_h, f, c, h, xh, it == 0);
    }
}

// Round 6
// 3012.403 us; speedup vs baseline: 1.3532x; 1.3532x over previous
//
#include <hip/hip_runtime.h>
#include <math.h>

#define NB    4096   // batch N
#define FEAT  1024
#define MSUP  512    // SUPPORT
#define G4    4096   // 4*FEAT
#define NWAYS 20     // n_ways fixed to 20 per setup_inputs()

typedef _Float16 f16;
typedef f16 f16x8 __attribute__((ext_vector_type(8)));
typedef f16 f16x4 __attribute__((ext_vector_type(4)));
typedef float f32x4 __attribute__((ext_vector_type(4)));
typedef unsigned int u32;
#define GLOBAL_AS __attribute__((address_space(1)))
#define LDS_AS    __attribute__((address_space(3)))

__device__ __forceinline__ void load_lds16(const void* g, void* l) {
    __builtin_amdgcn_global_load_lds((const GLOBAL_AS u32*)g, (LDS_AS u32*)l, 16, 0, 0);
}

// ---------------- f16 MFMA NT GEMM (R2-proven core): C[m,n] = sum_k A[m,k]*B[n,k]
// Up to THREE (A,B,K) pairs accumulated into the same C tile (null A terminates).
// 16x16x32 frags, row-major LDS tiles (R3/R4 lesson: leave the LDS layout alone).
// Optional two f32 per-column biases; OUTF16 selects f16 vs f32 output.
template<int BM, int BN, int WROWS, int WCOLS, bool OUTF16, bool HASBIAS>
__global__ __launch_bounds__(256) void mfma_nt(
    void* __restrict__ Cv, int ldc,
    const f16* __restrict__ A1, int lda1, const f16* __restrict__ B1, int ldb1, int K1,
    const f16* __restrict__ A2, int lda2, const f16* __restrict__ B2, int ldb2, int K2,
    const f16* __restrict__ A3, int lda3, const f16* __restrict__ B3, int ldb3, int K3,
    const float* __restrict__ bias1, const float* __restrict__ bias2)
{
    constexpr int BK = 32;                      // one 16x16x32 MFMA per K-step
    constexpr int WM = BM / WROWS, WN = BN / WCOLS;
    constexpr int FM = WM / 16,   FN = WN / 16;
    __shared__ f16 As[BM][BK];
    __shared__ f16 Bs[BN][BK];
    const int tid  = threadIdx.x;
    const int lane = tid & 63;
    const int wrow = (tid >> 6) % WROWS, wcol = (tid >> 6) / WROWS;
    const int bm = blockIdx.y * BM, bn = blockIdx.x * BN;
    const int lr = lane & 15, lq = lane >> 4;

    f32x4 acc[FM][FN] = {};

    #pragma unroll
    for (int pass = 0; pass < 3; ++pass) {
        const f16* A = pass == 0 ? A1 : (pass == 1 ? A2 : A3);
        const f16* B = pass == 0 ? B1 : (pass == 1 ? B2 : B3);
        const int lda = pass == 0 ? lda1 : (pass == 1 ? lda2 : lda3);
        const int ldb = pass == 0 ? ldb1 : (pass == 1 ? ldb2 : ldb3);
        const int K   = pass == 0 ? K1  : (pass == 1 ? K2  : K3);
        if (!A) break;                          // block-uniform
        #pragma unroll 1
        for (int k0 = 0; k0 < K; k0 += BK) {
            __syncthreads();
            // stage A tile: chunk c (16B) -> row c>>2, k-chunk c&3 (4 lanes = 64B/row)
            #pragma unroll
            for (int t = 0; t < (BM * 4) / 256; ++t) {
                int c = t * 256 + tid;
                load_lds16(A + (size_t)(bm + (c >> 2)) * lda + k0 + (c & 3) * 8,
                           &As[0][0] + ((size_t)t * 256 + (tid & 192)) * 8);
            }
            #pragma unroll
            for (int t = 0; t < (BN * 4) / 256; ++t) {
                int c = t * 256 + tid;
                load_lds16(B + (size_t)(bn + (c >> 2)) * ldb + k0 + (c & 3) * 8,
                           &Bs[0][0] + ((size_t)t * 256 + (tid & 192)) * 8);
            }
            __syncthreads();                    // drains vmcnt before ds_read
            f16x8 af[FM], bf[FN];
            #pragma unroll
            for (int i = 0; i < FM; ++i)
                af[i] = *(const f16x8*)&As[wrow * WM + i * 16 + lr][lq * 8];
            #pragma unroll
            for (int j = 0; j < FN; ++j)
                bf[j] = *(const f16x8*)&Bs[wcol * WN + j * 16 + lr][lq * 8];
            #pragma unroll
            for (int i = 0; i < FM; ++i)
                #pragma unroll
                for (int j = 0; j < FN; ++j)
                    acc[i][j] = __builtin_amdgcn_mfma_f32_16x16x32_f16(af[i], bf[j], acc[i][j], 0, 0, 0);
        }
    }

    // epilogue: C/D layout col=lane&15, row=(lane>>4)*4+reg (m89/m91-verified)
    #pragma unroll
    for (int i = 0; i < FM; ++i) {
        #pragma unroll
        for (int j = 0; j < FN; ++j) {
            const int col  = bn + wcol * WN + j * 16 + lr;
            const int row0 = bm + wrow * WM + i * 16 + lq * 4;
            float badd = 0.f;
            if (HASBIAS) badd = bias1[col] + bias2[col];
            #pragma unroll
            for (int r = 0; r < 4; ++r) {
                size_t off = (size_t)(row0 + r) * ldc + col;
                float v = acc[i][j][r] + badd;
                if (OUTF16) ((f16*)Cv)[off] = (f16)v;
                else        ((float*)Cv)[off] = v;
            }
        }
    }
}

// -------- softmax along contiguous rows; in f32 [rows][4096] -> out f16 --------
__global__ __launch_bounds__(256) void softmax_rows_kernel(
    const float* __restrict__ X, f16* __restrict__ Y)
{
    const int row = blockIdx.x;
    const float* x = X + (size_t)row * NB;
    f16* y = Y + (size_t)row * NB;
    const int tid = threadIdx.x;
    float v[16];
    float mx = -1e30f;
    #pragma unroll
    for (int i = 0; i < 16; ++i) { v[i] = x[tid + (i << 8)]; mx = fmaxf(mx, v[i]); }
    #pragma unroll
    for (int off = 32; off > 0; off >>= 1) mx = fmaxf(mx, __shfl_down(mx, off));
    __shared__ float sm[4];
    if ((tid & 63) == 0) sm[tid >> 6] = mx;
    __syncthreads();
    mx = fmaxf(fmaxf(sm[0], sm[1]), fmaxf(sm[2], sm[3]));
    float s = 0.f;
    #pragma unroll
    for (int i = 0; i < 16; ++i) { v[i] = __expf(v[i] - mx); s += v[i]; }
    #pragma unroll
    for (int off = 32; off > 0; off >>= 1) s += __shfl_down(s, off);
    __shared__ float ss[4];
    if ((tid & 63) == 0) ss[tid >> 6] = s;
    __syncthreads();
    s = ss[0] + ss[1] + ss[2] + ss[3];
    const float inv = 1.f / s;
    #pragma unroll
    for (int i = 0; i < 16; ++i) y[tid + (i << 8)] = (f16)(v[i] * inv);
}

// -------- transpose: f16 [R][C] -> f16 [C][R] --------
__global__ __launch_bounds__(256) void transpose_f16_kernel(
    const f16* __restrict__ in, f16* __restrict__ out, int R, int C)
{
    __shared__ f16 t[64][65];
    const int r0 = blockIdx.y * 64, c0 = blockIdx.x * 64;
    const int lr = threadIdx.x & 63, lw = threadIdx.x >> 6;
    #pragma unroll
    for (int i = 0; i < 16; ++i) {
        int rr = lw * 16 + i;
        t[rr][lr] = in[(size_t)(r0 + rr) * C + c0 + lr];
    }
    __syncthreads();
    #pragma unroll
    for (int i = 0; i < 16; ++i) {
        int cc = lw * 16 + i;
        out[(size_t)(c0 + cc) * R + r0 + lr] = t[lr][cc];
    }
}

// -------- f32 -> f16 convert --------
__global__ __launch_bounds__(256) void cvt_f16_kernel(
    const float* __restrict__ in, f16* __restrict__ out, int n)
{
    int idx = (blockIdx.x * 256 + threadIdx.x) * 4;
    if (idx < n) {
        float4 v = *(const float4*)(in + idx);
        f16x4 o = {(f16)v.x, (f16)v.y, (f16)v.z, (f16)v.w};
        *(f16x4*)(out + idx) = o;
    }
}

// -------- f32 -> (hi f16, lo f16) split: hi = f16(x), lo = f16(x - hi) --------
__global__ __launch_bounds__(256) void split_hilo_kernel(
    const float* __restrict__ in, f16* __restrict__ hi, f16* __restrict__ lo, int n)
{
    int idx = (blockIdx.x * 256 + threadIdx.x) * 4;
    if (idx < n) {
        float4 v = *(const float4*)(in + idx);
        f16x4 h = {(f16)v.x, (f16)v.y, (f16)v.z, (f16)v.w};
        f16x4 l = {(f16)(v.x - (float)h.x), (f16)(v.y - (float)h.y),
                   (f16)(v.z - (float)h.z), (f16)(v.w - (float)h.w)};
        *(f16x4*)(hi + idx) = h;
        *(f16x4*)(lo + idx) = l;
    }
}

// -------- LSTM cell (vectorized x4); gate = gates + pre; h = o*tanh(c)+f --------
// Writes f32 h to d_out and f16 h into h_h.
__global__ __launch_bounds__(256) void lstm_cell_kernel(
    const f16* __restrict__ gates, const f16* __restrict__ pre,
    const float* __restrict__ f,
    float* __restrict__ c, float* __restrict__ h, f16* __restrict__ h_h, int first)
{
    const int idx = (blockIdx.x * 256 + threadIdx.x) * 4;
    const int n = idx >> 10, k = idx & 1023;
    const f16* g = gates + (size_t)n * G4 + k;
    const f16* p = pre   + (size_t)n * G4 + k;
    f16x4 gi = *(const f16x4*)(g);
    f16x4 gf = *(const f16x4*)(g + 1024);
    f16x4 gg = *(const f16x4*)(g + 2048);
    f16x4 go = *(const f16x4*)(g + 3072);
    f16x4 pi = *(const f16x4*)(p);
    f16x4 pf = *(const f16x4*)(p + 1024);
    f16x4 pg = *(const f16x4*)(p + 2048);
    f16x4 po = *(const f16x4*)(p + 3072);
    float4 cold = {0.f, 0.f, 0.f, 0.f};
    if (!first) cold = *(const float4*)(c + idx);
    float4 fv = *(const float4*)(f + idx);
    float cn[4], hn[4];
    const float co[4] = {cold.x, cold.y, cold.z, cold.w};
    const float fo[4] = {fv.x, fv.y, fv.z, fv.w};
    #pragma unroll
    for (int u = 0; u < 4; ++u) {
        float ig = (float)gi[u] + (float)pi[u];
        float fg = (float)gf[u] + (float)pf[u];
        float g_ = (float)gg[u] + (float)pg[u];
        float og = (float)go[u] + (float)po[u];
        float i_ = 1.f / (1.f + __expf(-ig));
        float f_ = 1.f / (1.f + __expf(-fg));
        float gt = tanhf(g_);
        float o_ = 1.f / (1.f + __expf(-og));
        cn[u] = i_ * gt + f_ * co[u];
        hn[u] = o_ * tanhf(cn[u]) + fo[u];
    }
    *(float4*)(c + idx) = {cn[0], cn[1], cn[2], cn[3]};
    *(float4*)(h + idx) = {hn[0], hn[1], hn[2], hn[3]};
    f16x4 hh = {(f16)hn[0], (f16)hn[1], (f16)hn[2], (f16)hn[3]};
    *(f16x4*)(h_h + idx) = hh;
}

extern "C" void kernel_launch(void* const* d_in, const int* in_sizes, int n_in,
                              void* d_out, int out_size, void* d_ws, size_t ws_size,
                              hipStream_t stream) {
    const float* f   = (const float*)d_in[0];   // [NB, FEAT]
    const float* G   = (const float*)d_in[1];   // [MSUP, FEAT]
    const float* Wih = (const float*)d_in[2];   // [G4, 2*FEAT]
    const float* Whh = (const float*)d_in[3];   // [G4, FEAT]
    const float* bih = (const float*)d_in[4];   // [G4]
    const float* bhh = (const float*)d_in[5];   // [G4]
    float* h = (float*)d_out;                   // [NB, FEAT]

    char* W = (char*)d_ws;
    f16*   pre_h   = (f16*)(W);                          // 32 MB [NB][G4]
    f16*   gates_h = (f16*)(W + (size_t)(32 << 20));     // 32 MB [NB][G4]
    float* aT      = (float*)(W + (size_t)(64 << 20));   //  8 MB [MSUP][NB]
    f16*   aTh     = (f16*)(W + (size_t)(72 << 20));     //  4 MB [MSUP][NB]
    f16*   a_h     = (f16*)(W + (size_t)(76 << 20));     //  4 MB [NB][MSUP]
    float* c       = (float*)(W + (size_t)(80 << 20));   // 16 MB [NB][FEAT]
    f16*   h_h     = (f16*)(W + (size_t)(96 << 20));     //  8 MB [NB][FEAT] (init = f16(f))
    f16*   Wih_h   = (f16*)(W + (size_t)(104 << 20));    // 16 MB [G4][2F]
    f16*   Whh_h   = (f16*)(W + (size_t)(120 << 20));    //  8 MB [G4][F]
    float* Wr32    = (float*)(W + (size_t)(128 << 20));  //  8 MB [G4][MSUP] = W_r @ G^T (f32)
    f16*   Wr_hi   = (f16*)(W + (size_t)(136 << 20));    //  4 MB [G4][MSUP]
    f16*   Wr_lo   = (f16*)(W + (size_t)(140 << 20));    //  4 MB [G4][MSUP]
    f16*   G_h     = (f16*)(W + (size_t)(144 << 20));    //  1 MB [MSUP][FEAT]

    const f16* NF = nullptr;
    const dim3 blk(256);

    // conversions (every call — ws is re-poisoned)
    cvt_f16_kernel<<<(NB * FEAT) / 1024, blk, 0, stream>>>(f, h_h, NB * FEAT);          // h_0 = f
    cvt_f16_kernel<<<(G4 * 2 * FEAT) / 1024, blk, 0, stream>>>(Wih, Wih_h, G4 * 2 * FEAT);
    cvt_f16_kernel<<<(G4 * FEAT) / 1024, blk, 0, stream>>>(Whh, Whh_h, G4 * FEAT);
    cvt_f16_kernel<<<(MSUP * FEAT) / 1024, blk, 0, stream>>>(G, G_h, MSUP * FEAT);

    // pre = f @ W_f^T + b_ih + b_hh   (W_f = Wih[:, :FEAT]); constant across iterations
    mfma_nt<128, 128, 2, 2, true, true><<<dim3(G4 / 128, NB / 128), blk, 0, stream>>>(
        pre_h, G4,
        h_h, FEAT, Wih_h, 2 * FEAT, FEAT,
        NF, 0, NF, 0, 0,
        NF, 0, NF, 0, 0,
        bih, bhh);

    // Wr'[j][m] = sum_k W_r[j][k]*G[m][k] in f32, then hi/lo f16 split.
    // R5 lesson: single-f16 Wr' loses 0.2 absmax (softmax row-mass amplifies the
    // 2.8e-4 rounding); hi+lo makes the a@Wr' path MORE accurate than R2's
    // explicit r (no intermediate f16 rounding of r), at the same total K=2048.
    mfma_nt<128, 128, 2, 2, false, false><<<dim3(MSUP / 128, G4 / 128), blk, 0, stream>>>(
        Wr32, MSUP,
        Wih_h + FEAT, 2 * FEAT, G_h, FEAT, FEAT,
        NF, 0, NF, 0, 0,
        NF, 0, NF, 0, 0,
        nullptr, nullptr);
    split_hilo_kernel<<<(G4 * MSUP) / 1024, blk, 0, stream>>>(Wr32, Wr_hi, Wr_lo, G4 * MSUP);

    for (int it = 0; it < NWAYS; ++it) {
        // aT[m][n] = G[m]·h[n] (transposed → contiguous row softmax); 64x64 tiles
        // → 512 blocks (2/CU) vs 256 for occupancy.
        mfma_nt<64, 64, 2, 2, false, false><<<dim3(NB / 64, MSUP / 64), blk, 0, stream>>>(
            aT, NB,
            G_h, FEAT, h_h, FEAT, FEAT,
            NF, 0, NF, 0, 0,
            NF, 0, NF, 0, 0,
            nullptr, nullptr);

        softmax_rows_kernel<<<MSUP, blk, 0, stream>>>(aT, aTh);

        // a_h[n][m] = aTh[m][n]
        transpose_f16_kernel<<<dim3(NB / 64, MSUP / 64), blk, 0, stream>>>(aTh, a_h, MSUP, NB);

        // gates = a@Wr_hi^T + a@Wr_lo^T + h@Whh^T   (K = 512+512+1024; pre added in cell)
        mfma_nt<128, 128, 2, 2, true, false><<<dim3(G4 / 128, NB / 128), blk, 0, stream>>>(
            gates_h, G4,
            a_h, MSUP, Wr_hi, MSUP, MSUP,
            a_h, MSUP, Wr_lo, MSUP, MSUP,
            h_h, FEAT, Whh_h, FEAT, FEAT,
            nullptr, nullptr);

        lstm_cell_kernel<<<(NB * FEAT) / 1024, blk, 0, stream>>>(gates_h, pre_h, f, c, h, h_h, it == 0);
    }
}